// Round 1
// baseline (704.712 us; speedup 1.0000x reference)
//
#include <hip/hip_runtime.h>

#define B_    256
#define C_    10
#define T_    512
#define F_    48
#define DIN   480
#define H_    128
#define NOUT  36

// ---------------------------------------------------------------------------
// Transpose helper: dst[c*R + r] = src[r*C + c]   (src is [R][C] row-major)
// Used once per launch to build k-major weight copies in ws.
// ---------------------------------------------------------------------------
__global__ void k_transpose(const float* __restrict__ src, float* __restrict__ dst,
                            int R, int C) {
    int i = blockIdx.x * 256 + threadIdx.x;
    if (i < R * C) {
        int r = i / C, c = i % C;
        dst[c * R + r] = src[i];
    }
}

// ---------------------------------------------------------------------------
// GEMM1 fused: y = tanh(LayerNorm(x_reshaped @ Wi^T + bi))
// x: [B, C, T, F]; reshaped row (b,t) has d = c*F + f -> x[b][c][t][f].
// Block = 64 rows (one b, 64 consecutive t) x 128 cols. 256 thr, 4x8 microtile.
// K staged per-channel: each chunk is a contiguous [64x48] block of x. 
// ---------------------------------------------------------------------------
__global__ __launch_bounds__(256) void k_gemm1(
    const float* __restrict__ x, const float* __restrict__ Wit,  // Wit: [480][128] k-major
    const float* __restrict__ bi, const float* __restrict__ gamma,
    const float* __restrict__ betaln, float* __restrict__ y)
{
    __shared__ float xs[64][52];    // pad 48->52: 2-way max on A reads, float4-aligned
    __shared__ float wb[48][128];
    const int blk = blockIdx.x;
    const int b  = blk >> 3;          // 8 blocks per b (512/64)
    const int t0 = (blk & 7) << 6;
    const int tid = threadIdx.x;
    const int tr = tid >> 4, tc = tid & 15;

    float acc[4][8];
    #pragma unroll
    for (int i = 0; i < 4; ++i)
        #pragma unroll
        for (int j = 0; j < 8; ++j) acc[i][j] = 0.f;

    for (int c = 0; c < C_; ++c) {
        // ---- stage x tile: contiguous [64*48] floats ----
        const float4* src4 = (const float4*)(x + (((size_t)b * C_ + c) * T_ + t0) * F_);
        #pragma unroll
        for (int i = 0; i < 3; ++i) {
            int idx4 = tid + i * 256;        // 768 float4
            int row  = idx4 / 12;            // 12 float4 per 48-float row
            int col  = (idx4 % 12) << 2;
            *(float4*)&xs[row][col] = src4[idx4];
        }
        // ---- stage W tile: Wit rows [c*48, c*48+48) : contiguous 6144 floats ----
        const float4* w4 = (const float4*)(Wit + (size_t)c * 48 * 128);
        #pragma unroll
        for (int i = 0; i < 6; ++i)
            ((float4*)wb)[tid + i * 256] = w4[tid + i * 256];
        __syncthreads();

        #pragma unroll 4
        for (int kk = 0; kk < 48; ++kk) {
            float a0 = xs[tr * 4 + 0][kk];
            float a1 = xs[tr * 4 + 1][kk];
            float a2 = xs[tr * 4 + 2][kk];
            float a3 = xs[tr * 4 + 3][kk];
            float4 bv0 = *(const float4*)&wb[kk][tc * 8];
            float4 bv1 = *(const float4*)&wb[kk][tc * 8 + 4];
            float bv[8] = {bv0.x, bv0.y, bv0.z, bv0.w, bv1.x, bv1.y, bv1.z, bv1.w};
            #pragma unroll
            for (int j = 0; j < 8; ++j) {
                acc[0][j] += a0 * bv[j];
                acc[1][j] += a1 * bv[j];
                acc[2][j] += a2 * bv[j];
                acc[3][j] += a3 * bv[j];
            }
        }
        __syncthreads();
    }

    // ---- bias + LayerNorm over 128 (16 lanes share a row) + tanh ----
    float4 bi0 = *(const float4*)&bi[tc * 8];
    float4 bi1 = *(const float4*)&bi[tc * 8 + 4];
    float4 g0  = *(const float4*)&gamma[tc * 8];
    float4 g1  = *(const float4*)&gamma[tc * 8 + 4];
    float4 be0 = *(const float4*)&betaln[tc * 8];
    float4 be1 = *(const float4*)&betaln[tc * 8 + 4];
    float bia[8] = {bi0.x, bi0.y, bi0.z, bi0.w, bi1.x, bi1.y, bi1.z, bi1.w};
    float gg[8]  = {g0.x, g0.y, g0.z, g0.w, g1.x, g1.y, g1.z, g1.w};
    float bb[8]  = {be0.x, be0.y, be0.z, be0.w, be1.x, be1.y, be1.z, be1.w};

    #pragma unroll
    for (int i = 0; i < 4; ++i) {
        float s = 0.f, q = 0.f;
        #pragma unroll
        for (int j = 0; j < 8; ++j) {
            float v = acc[i][j] + bia[j];
            acc[i][j] = v;
            s += v; q += v * v;
        }
        #pragma unroll
        for (int m = 1; m < 16; m <<= 1) {
            s += __shfl_xor(s, m);
            q += __shfl_xor(q, m);
        }
        float mu  = s * (1.f / 128.f);
        float var = q * (1.f / 128.f) - mu * mu;
        float rstd = 1.0f / sqrtf(var + 1e-5f);
        float o[8];
        #pragma unroll
        for (int j = 0; j < 8; ++j)
            o[j] = tanhf((acc[i][j] - mu) * rstd * gg[j] + bb[j]);
        size_t row = (size_t)blk * 64 + tr * 4 + i;
        *(float4*)&y[row * 128 + tc * 8]     = make_float4(o[0], o[1], o[2], o[3]);
        *(float4*)&y[row * 128 + tc * 8 + 4] = make_float4(o[4], o[5], o[6], o[7]);
    }
}

// ---------------------------------------------------------------------------
// Generic [M x 128] @ [128 x 128] (Wt k-major: Wt[k][o]) + bias -> out
// Block = 64 rows, 256 thr, 4x8 microtile, K chunked by 32.
// ---------------------------------------------------------------------------
__global__ __launch_bounds__(256) void k_gemm128(
    const float* __restrict__ in, const float* __restrict__ Wt,
    const float* __restrict__ bias, float* __restrict__ out)
{
    __shared__ float xs[64][132];   // pad 128->132: 2-way max on A reads, f4-aligned
    __shared__ float wb[32][128];
    const int r0 = blockIdx.x * 64;
    const int tid = threadIdx.x;
    const int tr = tid >> 4, tc = tid & 15;

    const float4* in4 = (const float4*)(in + (size_t)r0 * 128);
    #pragma unroll
    for (int i = 0; i < 8; ++i) {
        int idx4 = tid + i * 256;       // 2048 float4
        int row  = idx4 >> 5;
        int col  = (idx4 & 31) << 2;
        *(float4*)&xs[row][col] = in4[idx4];
    }

    float acc[4][8];
    #pragma unroll
    for (int i = 0; i < 4; ++i)
        #pragma unroll
        for (int j = 0; j < 8; ++j) acc[i][j] = 0.f;

    for (int kc = 0; kc < 4; ++kc) {
        __syncthreads();                      // xs ready (kc=0) / wb consumed (kc>0)
        const float4* w4 = (const float4*)(Wt + (size_t)kc * 32 * 128);
        #pragma unroll
        for (int i = 0; i < 4; ++i)
            ((float4*)wb)[tid + i * 256] = w4[tid + i * 256];
        __syncthreads();

        #pragma unroll 4
        for (int kk = 0; kk < 32; ++kk) {
            int k = kc * 32 + kk;
            float a0 = xs[tr * 4 + 0][k];
            float a1 = xs[tr * 4 + 1][k];
            float a2 = xs[tr * 4 + 2][k];
            float a3 = xs[tr * 4 + 3][k];
            float4 bv0 = *(const float4*)&wb[kk][tc * 8];
            float4 bv1 = *(const float4*)&wb[kk][tc * 8 + 4];
            float bv[8] = {bv0.x, bv0.y, bv0.z, bv0.w, bv1.x, bv1.y, bv1.z, bv1.w};
            #pragma unroll
            for (int j = 0; j < 8; ++j) {
                acc[0][j] += a0 * bv[j];
                acc[1][j] += a1 * bv[j];
                acc[2][j] += a2 * bv[j];
                acc[3][j] += a3 * bv[j];
            }
        }
    }

    float4 bb0 = *(const float4*)&bias[tc * 8];
    float4 bb1 = *(const float4*)&bias[tc * 8 + 4];
    #pragma unroll
    for (int i = 0; i < 4; ++i) {
        size_t row = (size_t)r0 + tr * 4 + i;
        float4 o0 = make_float4(acc[i][0] + bb0.x, acc[i][1] + bb0.y,
                                acc[i][2] + bb0.z, acc[i][3] + bb0.w);
        float4 o1 = make_float4(acc[i][4] + bb1.x, acc[i][5] + bb1.y,
                                acc[i][6] + bb1.z, acc[i][7] + bb1.w);
        *(float4*)&out[row * 128 + tc * 8]     = o0;
        *(float4*)&out[row * 128 + tc * 8 + 4] = o1;
    }
}

// ---------------------------------------------------------------------------
// LIF scan over T=512. One thread per (b,h) chain. mul/add kept separate
// (no FMA contraction) to track the numpy reference at the spike threshold.
// ---------------------------------------------------------------------------
__global__ __launch_bounds__(64) void k_scan_spk(const float* __restrict__ cur,
                                                 float* __restrict__ spk)
{
    int g = blockIdx.x * 64 + threadIdx.x;   // 32768 chains
    int b = g >> 7;
    int h = g & 127;
    size_t base = (size_t)b * (T_ * H_) + h;
    float mem = 0.f;
    #pragma unroll 4
    for (int t = 0; t < T_; ++t) {
        float c = cur[base + (size_t)t * H_];
        mem = __fadd_rn(__fmul_rn(0.95f, mem), c);
        float s = mem > 1.0f ? 1.0f : 0.0f;
        spk[base + (size_t)t * H_] = s;
        mem -= s;
    }
}

__global__ __launch_bounds__(64) void k_scan_mean(const float* __restrict__ cur,
                                                  float* __restrict__ smean)
{
    int g = blockIdx.x * 64 + threadIdx.x;
    int b = g >> 7;
    int h = g & 127;
    size_t base = (size_t)b * (T_ * H_) + h;
    float mem = 0.f, sum = 0.f;
    #pragma unroll 4
    for (int t = 0; t < T_; ++t) {
        float c = cur[base + (size_t)t * H_];
        mem = __fadd_rn(__fmul_rn(0.95f, mem), c);
        float s = mem > 1.0f ? 1.0f : 0.0f;
        sum += s;
        mem -= s;
    }
    smean[g] = sum * (1.f / (float)T_);
}

// ---------------------------------------------------------------------------
// Readout: logits[b,o] = smean[b,:] . Wr[o,:] + br[o]; also writes trailing 0.
// ---------------------------------------------------------------------------
__global__ __launch_bounds__(64) void k_readout(const float* __restrict__ smean,
                                                const float* __restrict__ Wr,
                                                const float* __restrict__ br,
                                                float* __restrict__ out)
{
    __shared__ float sv[128];
    int b = blockIdx.x;
    int tid = threadIdx.x;
    sv[tid]      = smean[b * 128 + tid];
    sv[tid + 64] = smean[b * 128 + tid + 64];
    __syncthreads();
    if (tid < NOUT) {
        float a = br[tid];
        const float* wr = Wr + (size_t)tid * 128;
        #pragma unroll 8
        for (int h = 0; h < 128; ++h) a += sv[h] * wr[h];
        out[(size_t)b * NOUT + tid] = a;
    }
    if (b == 0 && tid == 0) out[(size_t)B_ * NOUT] = 0.0f;   // aux scalar output
}

// ---------------------------------------------------------------------------
extern "C" void kernel_launch(void* const* d_in, const int* in_sizes, int n_in,
                              void* d_out, int out_size, void* d_ws, size_t ws_size,
                              hipStream_t stream)
{
    const float* x      = (const float*)d_in[0];
    const float* Wi     = (const float*)d_in[1];
    const float* bi     = (const float*)d_in[2];
    const float* gamma  = (const float*)d_in[3];
    const float* betaln = (const float*)d_in[4];
    const float* W1     = (const float*)d_in[5];
    const float* b1     = (const float*)d_in[6];
    const float* W2     = (const float*)d_in[7];
    const float* b2     = (const float*)d_in[8];
    const float* Wr     = (const float*)d_in[9];
    const float* br     = (const float*)d_in[10];
    float* out = (float*)d_out;
    float* ws  = (float*)d_ws;

    // ws layout (floats): ~134.7 MB total
    float* Wit   = ws;                 // 480*128  = 61440
    float* W1t   = ws + 61440;         // 128*128  = 16384
    float* W2t   = ws + 77824;         // 128*128  = 16384
    float* smean = ws + 94208;         // 256*128  = 32768
    float* bufY  = ws + 131072;        // 131072*128 = 16777216  (y, then s1)
    float* bufC  = bufY + 16777216;    // 131072*128 = 16777216  (cur1, then cur2)

    k_transpose<<<(DIN * H_ + 255) / 256, 256, 0, stream>>>(Wi, Wit, H_, DIN);
    k_transpose<<<(H_ * H_ + 255) / 256, 256, 0, stream>>>(W1, W1t, H_, H_);
    k_transpose<<<(H_ * H_ + 255) / 256, 256, 0, stream>>>(W2, W2t, H_, H_);

    // y = tanh(LN(x@Wi^T + bi))
    k_gemm1<<<2048, 256, 0, stream>>>(x, Wit, bi, gamma, betaln, bufY);
    // cur1 = y @ W1^T + b1
    k_gemm128<<<2048, 256, 0, stream>>>(bufY, W1t, b1, bufC);
    // s1 = LIF scan(cur1)
    k_scan_spk<<<512, 64, 0, stream>>>(bufC, bufY);
    // cur2 = s1 @ W2^T + b2
    k_gemm128<<<2048, 256, 0, stream>>>(bufY, W2t, b2, bufC);
    // smean = mean_t LIF scan(cur2)
    k_scan_mean<<<512, 64, 0, stream>>>(bufC, smean);
    // logits
    k_readout<<<B_, 64, 0, stream>>>(smean, Wr, br, out);
}

// Round 2
// 539.978 us; speedup vs baseline: 1.3051x; 1.3051x over previous
//
#include <hip/hip_runtime.h>

#define B_    256
#define T_    512
#define H_    128
#define NOUT  36

typedef short bf16x8 __attribute__((ext_vector_type(8)));
typedef float f32x4  __attribute__((ext_vector_type(4)));

#define MFMA_BF16(a, b, c) __builtin_amdgcn_mfma_f32_16x16x32_bf16(a, b, c, 0, 0, 0)

__device__ __forceinline__ unsigned short f2bf(float f) {
    unsigned int u = __float_as_uint(f);
    return (unsigned short)((u + 0x7FFFu + ((u >> 16) & 1u)) >> 16);
}
__device__ __forceinline__ float bf2f(unsigned short s) {
    return __uint_as_float(((unsigned int)s) << 16);
}

// ---------------------------------------------------------------------------
// Weight prep: W [128][K] row-major -> k-inner-8 packed hi/lo bf16:
// dst[((k>>3)*128 + n)*8 + (k&7)] = bf16(W[n][k]) ; lo = residual.
// ---------------------------------------------------------------------------
__global__ void k_wprep(const float* __restrict__ W, unsigned short* __restrict__ hi,
                        unsigned short* __restrict__ lo, int K) {
    int i = blockIdx.x * 256 + threadIdx.x;   // i = k*128 + n
    if (i >= K * 128) return;
    int k = i >> 7, n = i & 127;
    float w = W[(size_t)n * K + k];
    unsigned short h = f2bf(w);
    unsigned short l = f2bf(w - bf2f(h));
    size_t d = ((size_t)(k >> 3) * 128 + n) * 8 + (k & 7);
    hi[d] = h; lo[d] = l;
}

// ---------------------------------------------------------------------------
// GEMM1: y = tanh(LN(x @ Wi^T + bi)), split-bf16 MFMA.
// Block: 128 rows (one b, 128 consecutive t) x 128 cols. 4 waves, each 32x128
// (full-N so LayerNorm stays in-wave). K=480 staged 96 (2 channels) at a time.
// Output packed u32 (hi<<16 | lo).
// ---------------------------------------------------------------------------
__global__ __launch_bounds__(256) void k_gemm1(
    const float* __restrict__ x, const unsigned short* __restrict__ Bh,
    const unsigned short* __restrict__ Bl, const float* __restrict__ bi,
    const float* __restrict__ gamma, const float* __restrict__ betaln,
    unsigned int* __restrict__ ypk)
{
    __shared__ unsigned short Ah[128 * 104];   // pad 96 -> 104 (2-way max)
    __shared__ unsigned short Al[128 * 104];
    const int blk = blockIdx.x;
    const int b = blk >> 2, t0 = (blk & 3) << 7;
    const int tid = threadIdx.x;
    const int w = tid >> 6, lane = tid & 63;
    const int g = lane >> 4, q = lane & 15;
    const int wrow = w * 32;

    f32x4 acc[2][8];
    #pragma unroll
    for (int mt = 0; mt < 2; ++mt)
        #pragma unroll
        for (int nt = 0; nt < 8; ++nt) acc[mt][nt] = (f32x4)0.0f;

    for (int c2 = 0; c2 < 5; ++c2) {
        if (c2) __syncthreads();
        // stage 2 channels: each a contiguous [128 x 48] fp32 block
        #pragma unroll
        for (int ch = 0; ch < 2; ++ch) {
            const float4* src = (const float4*)(x + (((size_t)b * 10 + c2 * 2 + ch) * T_ + t0) * 48);
            #pragma unroll
            for (int i = 0; i < 6; ++i) {
                int idx = tid + i * 256;          // < 1536
                int row = idx / 12;
                int col = (idx % 12) << 2;
                float4 v = src[idx];
                unsigned short h0 = f2bf(v.x), h1 = f2bf(v.y), h2 = f2bf(v.z), h3 = f2bf(v.w);
                ushort4 hv = { h0, h1, h2, h3 };
                ushort4 lv = { f2bf(v.x - bf2f(h0)), f2bf(v.y - bf2f(h1)),
                               f2bf(v.z - bf2f(h2)), f2bf(v.w - bf2f(h3)) };
                int a = row * 104 + ch * 48 + col;
                *(ushort4*)&Ah[a] = hv;
                *(ushort4*)&Al[a] = lv;
            }
        }
        __syncthreads();

        #pragma unroll
        for (int ks = 0; ks < 3; ++ks) {
            const int kofs = ks * 32 + g * 8;
            bf16x8 a_h[2], a_l[2];
            #pragma unroll
            for (int mt = 0; mt < 2; ++mt) {
                int ar = wrow + mt * 16 + q;
                a_h[mt] = *(const bf16x8*)&Ah[ar * 104 + kofs];
                a_l[mt] = *(const bf16x8*)&Al[ar * 104 + kofs];
            }
            const int kb = c2 * 12 + ks * 4 + g;
            bf16x8 b_h[8], b_l[8];
            #pragma unroll
            for (int nt = 0; nt < 8; ++nt) {
                size_t off = ((size_t)kb * 128 + nt * 16 + q) * 8;
                b_h[nt] = *(const bf16x8*)&Bh[off];
                b_l[nt] = *(const bf16x8*)&Bl[off];
            }
            #pragma unroll
            for (int mt = 0; mt < 2; ++mt)
                #pragma unroll
                for (int nt = 0; nt < 8; ++nt) {
                    acc[mt][nt] = MFMA_BF16(a_h[mt], b_h[nt], acc[mt][nt]);
                    acc[mt][nt] = MFMA_BF16(a_l[mt], b_h[nt], acc[mt][nt]);
                    acc[mt][nt] = MFMA_BF16(a_h[mt], b_l[nt], acc[mt][nt]);
                }
        }
    }

    // epilogue: bias + LayerNorm(128, in-wave) + tanh -> packed bf16 hi/lo
    float bia[8], gg[8], bb[8];
    #pragma unroll
    for (int nt = 0; nt < 8; ++nt) {
        int col = nt * 16 + q;
        bia[nt] = bi[col]; gg[nt] = gamma[col]; bb[nt] = betaln[col];
    }
    #pragma unroll
    for (int mt = 0; mt < 2; ++mt)
        #pragma unroll
        for (int j = 0; j < 4; ++j) {
            float v[8]; float s = 0.f, sq = 0.f;
            #pragma unroll
            for (int nt = 0; nt < 8; ++nt) {
                v[nt] = acc[mt][nt][j] + bia[nt];
                s += v[nt]; sq += v[nt] * v[nt];
            }
            #pragma unroll
            for (int m = 1; m < 16; m <<= 1) {
                s  += __shfl_xor(s, m);
                sq += __shfl_xor(sq, m);
            }
            float mu  = s * (1.f / 128.f);
            float var = sq * (1.f / 128.f) - mu * mu;
            float rstd = 1.0f / sqrtf(var + 1e-5f);
            size_t grow = (size_t)blk * 128 + wrow + mt * 16 + g * 4 + j;
            #pragma unroll
            for (int nt = 0; nt < 8; ++nt) {
                float o = tanhf((v[nt] - mu) * rstd * gg[nt] + bb[nt]);
                unsigned short h = f2bf(o);
                unsigned short l = f2bf(o - bf2f(h));
                ypk[grow * 128 + nt * 16 + q] = (((unsigned int)h) << 16) | l;
            }
        }
}

// ---------------------------------------------------------------------------
// GEMM2: cur1 = y @ W1^T + b1.  A = packed hi/lo y. 4 waves as 2x2 (64x64).
// ---------------------------------------------------------------------------
__global__ __launch_bounds__(256) void k_gemm2(
    const unsigned int* __restrict__ ypk, const unsigned short* __restrict__ Bh,
    const unsigned short* __restrict__ Bl, const float* __restrict__ bias,
    float* __restrict__ out)
{
    __shared__ unsigned short Ah[128 * 136];   // pad 128 -> 136 (2-way max)
    __shared__ unsigned short Al[128 * 136];
    const int r0 = blockIdx.x << 7;
    const int tid = threadIdx.x;
    const int w = tid >> 6, lane = tid & 63;
    const int g = lane >> 4, q = lane & 15;
    const int wrow = (w >> 1) * 64, wcol = (w & 1) * 64;

    const uint4* src = (const uint4*)(ypk + (size_t)r0 * 128);
    #pragma unroll
    for (int i = 0; i < 16; ++i) {
        int idx = tid + i * 256;          // < 4096
        int row = idx >> 5, q4 = idx & 31;
        uint4 vv = src[idx];
        ushort4 hv = { (unsigned short)(vv.x >> 16), (unsigned short)(vv.y >> 16),
                       (unsigned short)(vv.z >> 16), (unsigned short)(vv.w >> 16) };
        ushort4 lv = { (unsigned short)(vv.x & 0xffffu), (unsigned short)(vv.y & 0xffffu),
                       (unsigned short)(vv.z & 0xffffu), (unsigned short)(vv.w & 0xffffu) };
        int a = row * 136 + q4 * 4;
        *(ushort4*)&Ah[a] = hv;
        *(ushort4*)&Al[a] = lv;
    }
    __syncthreads();

    f32x4 acc[4][4];
    #pragma unroll
    for (int mt = 0; mt < 4; ++mt)
        #pragma unroll
        for (int nt = 0; nt < 4; ++nt) acc[mt][nt] = (f32x4)0.0f;

    #pragma unroll
    for (int ks = 0; ks < 4; ++ks) {
        const int kofs = ks * 32 + g * 8;
        bf16x8 a_h[4], a_l[4];
        #pragma unroll
        for (int mt = 0; mt < 4; ++mt) {
            int ar = wrow + mt * 16 + q;
            a_h[mt] = *(const bf16x8*)&Ah[ar * 136 + kofs];
            a_l[mt] = *(const bf16x8*)&Al[ar * 136 + kofs];
        }
        const int kb = ks * 4 + g;
        bf16x8 b_h[4], b_l[4];
        #pragma unroll
        for (int nt = 0; nt < 4; ++nt) {
            size_t off = ((size_t)kb * 128 + wcol + nt * 16 + q) * 8;
            b_h[nt] = *(const bf16x8*)&Bh[off];
            b_l[nt] = *(const bf16x8*)&Bl[off];
        }
        #pragma unroll
        for (int mt = 0; mt < 4; ++mt)
            #pragma unroll
            for (int nt = 0; nt < 4; ++nt) {
                acc[mt][nt] = MFMA_BF16(a_h[mt], b_h[nt], acc[mt][nt]);
                acc[mt][nt] = MFMA_BF16(a_l[mt], b_h[nt], acc[mt][nt]);
                acc[mt][nt] = MFMA_BF16(a_h[mt], b_l[nt], acc[mt][nt]);
            }
    }

    float bia[4];
    #pragma unroll
    for (int nt = 0; nt < 4; ++nt) bia[nt] = bias[wcol + nt * 16 + q];
    #pragma unroll
    for (int mt = 0; mt < 4; ++mt)
        #pragma unroll
        for (int nt = 0; nt < 4; ++nt)
            #pragma unroll
            for (int j = 0; j < 4; ++j) {
                size_t row = (size_t)r0 + wrow + mt * 16 + g * 4 + j;
                out[row * 128 + wcol + nt * 16 + q] = acc[mt][nt][j] + bia[nt];
            }
}

// ---------------------------------------------------------------------------
// GEMM3: cur2 = s1 @ W2^T + b2.  A = s1 bf16 (exact), 2 MFMA passes.
// ---------------------------------------------------------------------------
__global__ __launch_bounds__(256) void k_gemm3(
    const unsigned short* __restrict__ s1, const unsigned short* __restrict__ Bh,
    const unsigned short* __restrict__ Bl, const float* __restrict__ bias,
    float* __restrict__ out)
{
    __shared__ unsigned short As[128 * 136];
    const int r0 = blockIdx.x << 7;
    const int tid = threadIdx.x;
    const int w = tid >> 6, lane = tid & 63;
    const int g = lane >> 4, q = lane & 15;
    const int wrow = (w >> 1) * 64, wcol = (w & 1) * 64;

    const uint4* src = (const uint4*)(s1 + (size_t)r0 * 128);
    #pragma unroll
    for (int i = 0; i < 8; ++i) {
        int idx = tid + i * 256;          // < 2048 (16B = 8 bf16 each)
        int row = idx >> 4, q8 = idx & 15;
        uint4 vv = src[idx];
        *(uint4*)&As[row * 136 + q8 * 8] = vv;
    }
    __syncthreads();

    f32x4 acc[4][4];
    #pragma unroll
    for (int mt = 0; mt < 4; ++mt)
        #pragma unroll
        for (int nt = 0; nt < 4; ++nt) acc[mt][nt] = (f32x4)0.0f;

    #pragma unroll
    for (int ks = 0; ks < 4; ++ks) {
        const int kofs = ks * 32 + g * 8;
        bf16x8 a_s[4];
        #pragma unroll
        for (int mt = 0; mt < 4; ++mt) {
            int ar = wrow + mt * 16 + q;
            a_s[mt] = *(const bf16x8*)&As[ar * 136 + kofs];
        }
        const int kb = ks * 4 + g;
        bf16x8 b_h[4], b_l[4];
        #pragma unroll
        for (int nt = 0; nt < 4; ++nt) {
            size_t off = ((size_t)kb * 128 + wcol + nt * 16 + q) * 8;
            b_h[nt] = *(const bf16x8*)&Bh[off];
            b_l[nt] = *(const bf16x8*)&Bl[off];
        }
        #pragma unroll
        for (int mt = 0; mt < 4; ++mt)
            #pragma unroll
            for (int nt = 0; nt < 4; ++nt) {
                acc[mt][nt] = MFMA_BF16(a_s[mt], b_h[nt], acc[mt][nt]);
                acc[mt][nt] = MFMA_BF16(a_s[mt], b_l[nt], acc[mt][nt]);
            }
    }

    float bia[4];
    #pragma unroll
    for (int nt = 0; nt < 4; ++nt) bia[nt] = bias[wcol + nt * 16 + q];
    #pragma unroll
    for (int mt = 0; mt < 4; ++mt)
        #pragma unroll
        for (int nt = 0; nt < 4; ++nt)
            #pragma unroll
            for (int j = 0; j < 4; ++j) {
                size_t row = (size_t)r0 + wrow + mt * 16 + g * 4 + j;
                out[row * 128 + wcol + nt * 16 + q] = acc[mt][nt][j] + bia[nt];
            }
}

// ---------------------------------------------------------------------------
// LIF scans. One thread per (b,h) chain; unroll 32 for load pipelining.
// ---------------------------------------------------------------------------
__global__ __launch_bounds__(256) void k_scan1(const float* __restrict__ cur,
                                               unsigned short* __restrict__ spk)
{
    int gid = blockIdx.x * 256 + threadIdx.x;
    int b = gid >> 7, h = gid & 127;
    size_t base = (size_t)b * (T_ * H_) + h;
    float mem = 0.f;
    #pragma unroll 32
    for (int t = 0; t < T_; ++t) {
        float c = cur[base + (size_t)t * H_];
        mem = __fadd_rn(__fmul_rn(0.95f, mem), c);
        unsigned short sp; float sv;
        if (mem > 1.0f) { sp = 0x3F80u; sv = 1.0f; } else { sp = 0u; sv = 0.f; }
        spk[base + (size_t)t * H_] = sp;
        mem -= sv;
    }
}

__global__ __launch_bounds__(256) void k_scan2(const float* __restrict__ cur,
                                               float* __restrict__ smean)
{
    int gid = blockIdx.x * 256 + threadIdx.x;
    int b = gid >> 7, h = gid & 127;
    size_t base = (size_t)b * (T_ * H_) + h;
    float mem = 0.f, sum = 0.f;
    #pragma unroll 32
    for (int t = 0; t < T_; ++t) {
        float c = cur[base + (size_t)t * H_];
        mem = __fadd_rn(__fmul_rn(0.95f, mem), c);
        float sv = (mem > 1.0f) ? 1.0f : 0.0f;
        sum += sv;
        mem -= sv;
    }
    smean[gid] = sum * (1.f / (float)T_);
}

// ---------------------------------------------------------------------------
// Readout
// ---------------------------------------------------------------------------
__global__ __launch_bounds__(64) void k_readout(const float* __restrict__ smean,
                                                const float* __restrict__ Wr,
                                                const float* __restrict__ br,
                                                float* __restrict__ out)
{
    __shared__ float sv[128];
    int b = blockIdx.x;
    int tid = threadIdx.x;
    sv[tid]      = smean[b * 128 + tid];
    sv[tid + 64] = smean[b * 128 + tid + 64];
    __syncthreads();
    if (tid < NOUT) {
        float a = br[tid];
        const float* wr = Wr + (size_t)tid * 128;
        #pragma unroll 8
        for (int h = 0; h < 128; ++h) a += sv[h] * wr[h];
        out[(size_t)b * NOUT + tid] = a;
    }
    if (b == 0 && tid == 0) out[(size_t)B_ * NOUT] = 0.0f;
}

// ---------------------------------------------------------------------------
extern "C" void kernel_launch(void* const* d_in, const int* in_sizes, int n_in,
                              void* d_out, int out_size, void* d_ws, size_t ws_size,
                              hipStream_t stream)
{
    (void)in_sizes; (void)n_in; (void)out_size; (void)ws_size;
    const float* x      = (const float*)d_in[0];
    const float* Wi     = (const float*)d_in[1];
    const float* bi     = (const float*)d_in[2];
    const float* gamma  = (const float*)d_in[3];
    const float* betaln = (const float*)d_in[4];
    const float* W1     = (const float*)d_in[5];
    const float* b1     = (const float*)d_in[6];
    const float* W2     = (const float*)d_in[7];
    const float* b2     = (const float*)d_in[8];
    const float* Wr     = (const float*)d_in[9];
    const float* br     = (const float*)d_in[10];
    float* out = (float*)d_out;
    float* ws  = (float*)d_ws;

    // ws layout (float units), ~134.7 MB total — same footprint as R1:
    // shorts: Wib_h[61440] Wib_l[61440] W1b_h/l[16384 ea] W2b_h/l[16384 ea]
    unsigned short* us    = (unsigned short*)ws;
    unsigned short* Wib_h = us;                 // shorts [0, 61440)
    unsigned short* Wib_l = us + 61440;         // [61440, 122880)
    unsigned short* W1b_h = us + 122880;        // [122880, 139264)
    unsigned short* W1b_l = us + 139264;
    unsigned short* W2b_h = us + 155648;
    unsigned short* W2b_l = us + 172032;        // ends 188416 shorts = 94208 floats
    float*          smean = ws + 94208;         // 32768 floats
    unsigned int*   ypk   = (unsigned int*)(ws + 131072);     // 16777216 u32
    unsigned short* s1    = (unsigned short*)(ws + 131072);   // reuses ypk region
    float*          cur   = ws + 131072 + 16777216;           // 16777216 f32

    k_wprep<<<(480 * 128 + 255) / 256, 256, 0, stream>>>(Wi, Wib_h, Wib_l, 480);
    k_wprep<<<(128 * 128 + 255) / 256, 256, 0, stream>>>(W1, W1b_h, W1b_l, 128);
    k_wprep<<<(128 * 128 + 255) / 256, 256, 0, stream>>>(W2, W2b_h, W2b_l, 128);

    k_gemm1<<<1024, 256, 0, stream>>>(x, Wib_h, Wib_l, bi, gamma, betaln, ypk);
    k_gemm2<<<1024, 256, 0, stream>>>(ypk, W1b_h, W1b_l, b1, cur);
    k_scan1<<<128, 256, 0, stream>>>(cur, s1);
    k_gemm3<<<1024, 256, 0, stream>>>(s1, W2b_h, W2b_l, b2, cur);
    k_scan2<<<128, 256, 0, stream>>>(cur, smean);
    k_readout<<<B_, 64, 0, stream>>>(smean, Wr, br, out);
}